// Round 6
// baseline (350.404 us; speedup 1.0000x reference)
//
#include <hip/hip_runtime.h>

// Problem constants
#define Bn 8
#define Tn 2048
#define Dn 1024
#define Hn 1024
#define Mn (Bn * Tn)  // 16384 flattened rows of x

typedef __attribute__((ext_vector_type(8))) short bf16x8;    // 8 bf16 = 4 VGPRs (MFMA A/B frag)
typedef __attribute__((ext_vector_type(4))) short short4v;   // 4 bf16 = 8B store
typedef __attribute__((ext_vector_type(4))) float f32x4;     // 16x16 MFMA C/D frag

__device__ __forceinline__ unsigned short f2bf(float f) {
  union { float f; unsigned int u; } v; v.f = f;
  unsigned int u = v.u;
  u += 0x7FFFu + ((u >> 16) & 1u);   // RNE
  return (unsigned short)(u >> 16);
}
__device__ __forceinline__ float bf2f(unsigned short h) {
  union { unsigned int u; float f; } v; v.u = ((unsigned int)h) << 16;
  return v.f;
}

// async global->LDS, 16B per lane; lds base must be wave-uniform (lane writes base + lane*16B)
__device__ __forceinline__ void gload_lds16(const unsigned short* g, unsigned short* l) {
  __builtin_amdgcn_global_load_lds((const __attribute__((address_space(1))) void*)g,
                                   (__attribute__((address_space(3))) void*)l, 16, 0, 0);
}

// Chunk swizzle s(r) = (r&3) ^ ((r>>2)&3): LDS slot (row, q) holds global 16B chunk q ^ s(row).
// A full-wave rd4 reads 16 whole 64B rows -> covers all 32 banks exactly 8x.

// Swizzled staging of a 128x32-short tile (4 waves x 32 rows). 2 vmem loads/lane.
__device__ __forceinline__ void stage128x32s(const unsigned short* gbase, size_t row_stride,
                                             unsigned short* lds, int wave, int lane) {
#pragma unroll
  for (int c = 0; c < 2; ++c) {
    int rl = c * 16 + (lane >> 2);          // row within this wave's 32-row strip
    int pos = (lane & 3) ^ (rl & 3) ^ ((rl >> 2) & 3);
    const unsigned short* g = gbase + (size_t)(wave * 32 + rl) * row_stride + pos * 8;
    gload_lds16(g, lds + (wave * 32 + c * 16) * 32);
  }
}

// Swizzled staging of a 256x32-short tile (8 waves x 32 rows). Same swizzle. 2 vmem/lane.
__device__ __forceinline__ void stage256x32s(const unsigned short* gbase, size_t row_stride,
                                             unsigned short* lds, int wave, int lane) {
#pragma unroll
  for (int c = 0; c < 2; ++c) {
    int rl = c * 16 + (lane >> 2);
    int pos = (lane & 3) ^ (rl & 3) ^ ((rl >> 2) & 3);
    const unsigned short* g = gbase + (size_t)(wave * 32 + rl) * row_stride + pos * 8;
    gload_lds16(g, lds + (wave * 32 + c * 16) * 32);
  }
}

// 16x16x32 fragment quad read: 4 consecutive 16-row groups at fixed k-group, swizzled chunk.
__device__ __forceinline__ void rd4(const unsigned short* p, int rbase, int rl15, int csw,
                                    bf16x8 fr[4]) {
#pragma unroll
  for (int m = 0; m < 4; ++m)
    fr[m] = *(const bf16x8*)&p[(rbase + m * 16 + rl15) * 32 + csw * 8];
}

#define QKV_BAR  __builtin_amdgcn_s_barrier()
#define QKV_LGKM asm volatile("s_waitcnt lgkmcnt(0)" ::: "memory")
#define QKV_VM8  asm volatile("s_waitcnt vmcnt(8)" ::: "memory")
#define QKV_VM4  asm volatile("s_waitcnt vmcnt(4)" ::: "memory")
#define QKV_VM0  asm volatile("s_waitcnt vmcnt(0)" ::: "memory")

// ---------------- fp32 -> bf16 convert (x) ----------------
__global__ __launch_bounds__(256) void k_convert(const float* __restrict__ in,
                                                 unsigned short* __restrict__ out, int n4) {
  int idx = blockIdx.x * 256 + threadIdx.x;
  if (idx >= n4) return;
  float4 v = ((const float4*)in)[idx];
  short4v o;
  o.x = (short)f2bf(v.x); o.y = (short)f2bf(v.y);
  o.z = (short)f2bf(v.z); o.w = (short)f2bf(v.w);
  *(short4v*)(out + (size_t)idx * 4) = o;
}

// ---------------- W fp32 [k][n] -> bf16 Wt [n][k], 3 weights in one dispatch ----------------
__global__ __launch_bounds__(256) void k_cvt_w_t(const float* __restrict__ W0,
                                                 const float* __restrict__ W1,
                                                 const float* __restrict__ W2,
                                                 unsigned short* __restrict__ Wt3) {
  const int n0 = blockIdx.x * 64, k0 = blockIdx.y * 64, w = blockIdx.z;
  const float* W = (w == 0) ? W0 : (w == 1) ? W1 : W2;
  unsigned short* Wt = Wt3 + (size_t)w * Hn * Dn;
  __shared__ unsigned short lT[64 * 65];
  const int tid = threadIdx.x;
#pragma unroll
  for (int p = 0; p < 2; ++p) {
    int o = tid + p * 256;
    int r = o >> 3, c = (o & 7) * 8;  // r = k offset, c = n offset
    const float* src = W + (size_t)(k0 + r) * Hn + n0 + c;
    float4 v0 = *(const float4*)src;
    float4 v1 = *(const float4*)(src + 4);
    unsigned short* d = &lT[r * 65 + c];
    d[0] = f2bf(v0.x); d[1] = f2bf(v0.y); d[2] = f2bf(v0.z); d[3] = f2bf(v0.w);
    d[4] = f2bf(v1.x); d[5] = f2bf(v1.y); d[6] = f2bf(v1.z); d[7] = f2bf(v1.w);
  }
  __syncthreads();
#pragma unroll
  for (int p = 0; p < 2; ++p) {
    int o = tid + p * 256;
    int r2 = o >> 3, c2 = (o & 7) * 8;  // r2 = n offset, c2 = k offset
    bf16x8 v;
#pragma unroll
    for (int s = 0; s < 8; ++s) v[s] = (short)lT[(c2 + s) * 65 + r2];
    *(bf16x8*)(Wt + (size_t)(n0 + r2) * Dn + k0 + c2) = v;
  }
}

// ---------------- Merged QKV projection GEMM: 256x256 tile, 2-phase-per-K-tile pipeline ----
// (unchanged from R5 passing version: 124 us, Mfma 34.7%)
__global__ __launch_bounds__(512, 2) void gemm_qkv(const unsigned short* __restrict__ A,
                                                   const unsigned short* __restrict__ Wt3,
                                                   unsigned short* __restrict__ Q,
                                                   unsigned short* __restrict__ Kb,
                                                   unsigned short* __restrict__ Vt) {
  const int f = blockIdx.x;
  const int c = f & 7;
  const int q = f >> 3;
  const int nn = q % 12;
  const int w = nn >> 2;                     // 0=Q 1=K 2=V
  const int n0 = (nn & 3) * 256;
  const int m0 = ((q / 12) * 8 + c) * 256;   // m-tile pinned to XCD c
  const unsigned short* Bw = Wt3 + (size_t)w * Hn * Dn;
  __shared__ unsigned short lds[2][4][256 * 32];  // [buf][AL,AH,BL,BH]; buf0 = even tiles
  const int tid = threadIdx.x;
  const int lane = tid & 63, wave = tid >> 6;
  const int wr = (wave >> 2) * 128;          // wave 128-row strip
  const int wc = (wave & 3) * 64;            // wave 64-col strip
  const int rl15 = lane & 15, l4 = lane >> 4;
  const int csw = (l4 ^ (lane & 3) ^ ((lane >> 2) & 3)) & 3;  // = l4 ^ s(row)

  f32x4 acc[8][4];
#pragma unroll
  for (int m = 0; m < 8; ++m)
#pragma unroll
    for (int n = 0; n < 4; ++n) acc[m][n] = (f32x4)(0.f);

  const unsigned short* Ab = A + (size_t)m0 * Dn;
  const unsigned short* Bb = Bw + (size_t)n0 * Dn;

  unsigned short* L0AL = &lds[0][0][0];
  unsigned short* L0AH = &lds[0][1][0];
  unsigned short* L0BL = &lds[0][2][0];
  unsigned short* L0BH = &lds[0][3][0];
  unsigned short* L1AL = &lds[1][0][0];
  unsigned short* L1AH = &lds[1][1][0];
  unsigned short* L1BL = &lds[1][2][0];
  unsigned short* L1BH = &lds[1][3][0];

  bf16x8 a0[4], a1[4], b0[4];
  auto RP = [&](const unsigned short* pa, const unsigned short* pb) {
    rd4(pa, wr, rl15, csw, a0);
    rd4(pa, wr + 64, rl15, csw, a1);
    rd4(pb, wc, rl15, csw, b0);
  };
  auto M32 = [&]() {
    __builtin_amdgcn_s_setprio(1);
#pragma unroll
    for (int m = 0; m < 4; ++m)
#pragma unroll
      for (int n = 0; n < 4; ++n)
        acc[m][n] = __builtin_amdgcn_mfma_f32_16x16x32_bf16(a0[m], b0[n], acc[m][n], 0, 0, 0);
#pragma unroll
    for (int m = 0; m < 4; ++m)
#pragma unroll
      for (int n = 0; n < 4; ++n)
        acc[m + 4][n] = __builtin_amdgcn_mfma_f32_16x16x32_bf16(a1[m], b0[n], acc[m + 4][n], 0, 0, 0);
    __builtin_amdgcn_s_setprio(0);
  };

  stage256x32s(Ab +  0, Dn, L0AL, wave, lane);
  stage256x32s(Bb +  0, Dn, L0BL, wave, lane);
  stage256x32s(Ab + 32, Dn, L0AH, wave, lane);
  stage256x32s(Bb + 32, Dn, L0BH, wave, lane);
  stage256x32s(Ab + 64, Dn, L1AL, wave, lane);
  stage256x32s(Bb + 64, Dn, L1BL, wave, lane);
  QKV_VM8;
  QKV_BAR;

#pragma unroll 1
  for (int i = 0; i < 6; ++i) {
    const int s1 = 2 * i + 1, s2 = 2 * i + 2, s3 = 2 * i + 3;
    RP(L0AL, L0BL);
    stage256x32s(Ab + s1 * 64 + 32, Dn, L1AH, wave, lane);
    stage256x32s(Bb + s1 * 64 + 32, Dn, L1BH, wave, lane);
    QKV_VM8; QKV_BAR; QKV_LGKM; M32(); QKV_BAR;
    RP(L0AH, L0BH);
    stage256x32s(Ab + s2 * 64, Dn, L0AL, wave, lane);
    stage256x32s(Bb + s2 * 64, Dn, L0BL, wave, lane);
    QKV_VM8; QKV_BAR; QKV_LGKM; M32(); QKV_BAR;
    RP(L1AL, L1BL);
    stage256x32s(Ab + s2 * 64 + 32, Dn, L0AH, wave, lane);
    stage256x32s(Bb + s2 * 64 + 32, Dn, L0BH, wave, lane);
    QKV_VM8; QKV_BAR; QKV_LGKM; M32(); QKV_BAR;
    RP(L1AH, L1BH);
    stage256x32s(Ab + s3 * 64, Dn, L1AL, wave, lane);
    stage256x32s(Bb + s3 * 64, Dn, L1BL, wave, lane);
    QKV_VM8; QKV_BAR; QKV_LGKM; M32(); QKV_BAR;
  }
  RP(L0AL, L0BL);
  stage256x32s(Ab + 13 * 64 + 32, Dn, L1AH, wave, lane);
  stage256x32s(Bb + 13 * 64 + 32, Dn, L1BH, wave, lane);
  QKV_VM8; QKV_BAR; QKV_LGKM; M32(); QKV_BAR;
  RP(L0AH, L0BH);
  stage256x32s(Ab + 14 * 64, Dn, L0AL, wave, lane);
  stage256x32s(Bb + 14 * 64, Dn, L0BL, wave, lane);
  QKV_VM8; QKV_BAR; QKV_LGKM; M32(); QKV_BAR;
  RP(L1AL, L1BL);
  stage256x32s(Ab + 14 * 64 + 32, Dn, L0AH, wave, lane);
  stage256x32s(Bb + 14 * 64 + 32, Dn, L0BH, wave, lane);
  QKV_VM8; QKV_BAR; QKV_LGKM; M32(); QKV_BAR;
  RP(L1AH, L1BH);
  stage256x32s(Ab + 15 * 64, Dn, L1AL, wave, lane);
  stage256x32s(Bb + 15 * 64, Dn, L1BL, wave, lane);
  QKV_VM8; QKV_BAR; QKV_LGKM; M32(); QKV_BAR;
  RP(L0AL, L0BL);
  stage256x32s(Ab + 15 * 64 + 32, Dn, L1AH, wave, lane);
  stage256x32s(Bb + 15 * 64 + 32, Dn, L1BH, wave, lane);
  QKV_VM8; QKV_BAR; QKV_LGKM; M32(); QKV_BAR;
  RP(L0AH, L0BH);
  QKV_VM4; QKV_BAR; QKV_LGKM; M32(); QKV_BAR;
  RP(L1AL, L1BL);
  QKV_VM0; QKV_BAR; QKV_LGKM; M32(); QKV_BAR;
  RP(L1AH, L1BH);
  QKV_LGKM; M32();

  if (w != 2) {
    unsigned short* Cp = (w == 0) ? Q : Kb;
#pragma unroll
    for (int m = 0; m < 8; ++m) {
      const int row = m0 + wr + m * 16 + l4 * 4;
#pragma unroll
      for (int n = 0; n < 4; ++n) {
        const int col = n0 + wc + n * 16 + rl15;
#pragma unroll
        for (int r = 0; r < 4; ++r)
          Cp[(size_t)(row + r) * Hn + col] = f2bf(acc[m][n][r]);
      }
    }
  } else {
    const int bb = m0 >> 11;
    const int tb = m0 & 2047;
#pragma unroll
    for (int m = 0; m < 8; ++m) {
      const int t0 = tb + wr + m * 16 + l4 * 4;
#pragma unroll
      for (int n = 0; n < 4; ++n) {
        const int h = n0 + wc + n * 16 + rl15;
        short4v o;
        o.x = (short)f2bf(acc[m][n][0]);
        o.y = (short)f2bf(acc[m][n][1]);
        o.z = (short)f2bf(acc[m][n][2]);
        o.w = (short)f2bf(acc[m][n][3]);
        *(short4v*)(Vt + ((size_t)bb * Hn + h) * Tn + t0) = o;
      }
    }
  }
}

// ---------------- Scores: 128^2 tile, 256 thr, 64KB LDS (2 blocks/CU), counted-vmcnt ----
// E[i][j] = exp((Q[i].K[j])/32), causal-masked to 0, bf16 store; FUSED row sums via
// 16-lane shfl reduce + one atomicAdd per row per col-wave (sums the bf16-rounded E for
// numerical consistency with the stored numerators). Triangular grid: 8 batches x 136
// causal tiles; batch = f&7 pins each batch's Q/K panels to one XCD.
// Pipeline: generic 2-phase/K-tile counted-vmcnt loop (same ledger as gemm_qkv; stages
// past the last tile clamp to tile nkt-1 and land in dead slots, keeping vmcnt uniform).
__global__ __launch_bounds__(256, 2) void gemm_scores(const unsigned short* __restrict__ Q,
                                                      const unsigned short* __restrict__ K,
                                                      unsigned short* __restrict__ S,
                                                      float* __restrict__ lrow) {
  const int f = blockIdx.x;
  const int b = f & 7;
  const int u = f >> 3;
  int rt = (int)((sqrtf(8.f * (float)u + 1.f) - 1.f) * 0.5f);
  if ((rt + 1) * (rt + 2) / 2 <= u) ++rt;
  if (rt * (rt + 1) / 2 > u) --rt;
  const int ct = u - rt * (rt + 1) / 2;
  const int i0 = rt * 128, j0 = ct * 128;
  const unsigned short* Ag = Q + (size_t)b * Tn * Hn + (size_t)i0 * Hn;
  const unsigned short* Bg = K + (size_t)b * Tn * Hn + (size_t)j0 * Hn;
  unsigned short* Sb = S + (size_t)b * Tn * Tn;
  __shared__ unsigned short lds[2][4][128 * 32];  // [buf][AL,AH,BL,BH] = 64 KiB
  const int tid = threadIdx.x;
  const int lane = tid & 63, wave = tid >> 6;
  const int wr = (wave >> 1) * 64, wc = (wave & 1) * 64;
  const int rl15 = lane & 15, l4 = lane >> 4;
  const int csw = (l4 ^ (lane & 3) ^ ((lane >> 2) & 3)) & 3;

  f32x4 acc[4][4];
#pragma unroll
  for (int m = 0; m < 4; ++m)
#pragma unroll
    for (int n = 0; n < 4; ++n) acc[m][n] = (f32x4)(0.f);

  bf16x8 a0[4], b0[4];
  auto M16 = [&]() {
    __builtin_amdgcn_s_setprio(1);
#pragma unroll
    for (int m = 0; m < 4; ++m)
#pragma unroll
      for (int n = 0; n < 4; ++n)
        acc[m][n] = __builtin_amdgcn_mfma_f32_16x16x32_bf16(a0[m], b0[n], acc[m][n], 0, 0, 0);
    __builtin_amdgcn_s_setprio(0);
  };

  const int nkt = Hn / 64;
  // prologue: {AL,BL,AH,BH}(0), {AL,BL}(1) = 12 loads; VM8 drains AL0,BL0
  stage128x32s(Ag +  0, Hn, &lds[0][0][0], wave, lane);
  stage128x32s(Bg +  0, Hn, &lds[0][2][0], wave, lane);
  stage128x32s(Ag + 32, Hn, &lds[0][1][0], wave, lane);
  stage128x32s(Bg + 32, Hn, &lds[0][3][0], wave, lane);
  stage128x32s(Ag + 64, Hn, &lds[1][0][0], wave, lane);
  stage128x32s(Bg + 64, Hn, &lds[1][2][0], wave, lane);
  QKV_VM8; QKV_BAR;

#pragma unroll 1
  for (int t = 0; t < nkt; ++t) {
    const int cb = t & 1, nb = cb ^ 1;
    // A-phase: k-lo; stage {AH,BH}(t+1) (clamped)
    rd4(&lds[cb][0][0], wr, rl15, csw, a0);
    rd4(&lds[cb][2][0], wc, rl15, csw, b0);
    {
      const int ts = (t + 1 < nkt) ? t + 1 : nkt - 1;
      stage128x32s(Ag + ts * 64 + 32, Hn, &lds[nb][1][0], wave, lane);
      stage128x32s(Bg + ts * 64 + 32, Hn, &lds[nb][3][0], wave, lane);
    }
    QKV_VM8; QKV_BAR; QKV_LGKM; M16(); QKV_BAR;
    // B-phase: k-hi; stage {AL,BL}(t+2) (clamped; slot parity (t+2)&1 == cb)
    rd4(&lds[cb][1][0], wr, rl15, csw, a0);
    rd4(&lds[cb][3][0], wc, rl15, csw, b0);
    {
      const int ts = (t + 2 < nkt) ? t + 2 : nkt - 1;
      stage128x32s(Ag + ts * 64, Hn, &lds[cb][0][0], wave, lane);
      stage128x32s(Bg + ts * 64, Hn, &lds[cb][2][0], wave, lane);
    }
    QKV_VM8; QKV_BAR; QKV_LGKM; M16(); QKV_BAR;
  }
  QKV_VM0;  // drain dummies before LDS dealloc/exit

  // epilogue: E store + fused row partial sums
  float rs[4][4];
#pragma unroll
  for (int m = 0; m < 4; ++m)
#pragma unroll
    for (int r = 0; r < 4; ++r) rs[m][r] = 0.f;
#pragma unroll
  for (int m = 0; m < 4; ++m) {
    const int row = i0 + wr + m * 16 + l4 * 4;
#pragma unroll
    for (int n = 0; n < 4; ++n) {
      const int col = j0 + wc + n * 16 + rl15;
#pragma unroll
      for (int r = 0; r < 4; ++r) {
        float e = (col <= row + r) ? __expf(acc[m][n][r] * 0.03125f) : 0.f;
        unsigned short eb = f2bf(e);
        Sb[(size_t)(row + r) * Tn + col] = eb;
        rs[m][r] += bf2f(eb);
      }
    }
  }
#pragma unroll
  for (int m = 0; m < 4; ++m)
#pragma unroll
    for (int r = 0; r < 4; ++r) {
#pragma unroll
      for (int msk = 1; msk < 16; msk <<= 1)
        rs[m][r] += __shfl_xor(rs[m][r], msk);
      if (rl15 == 0)
        atomicAdd(&lrow[(size_t)b * Tn + i0 + wr + m * 16 + l4 * 4 + r], rs[m][r]);
    }
}

// ---------------- Output: 128^2 tile, 256 thr, 64KB LDS (2 blocks/CU), counted-vmcnt ----
// O[i][h] = (1/l_i) * sum_k E[i][k] * Vt[h][k]; causal K range nkt = 2*(rt+1);
// same generic clamped-stage pipeline as gemm_scores.
__global__ __launch_bounds__(256, 2) void gemm_out(const unsigned short* __restrict__ P,
                                                   const unsigned short* __restrict__ Vt,
                                                   const float* __restrict__ lbuf,
                                                   float* __restrict__ O) {
  const int f = blockIdx.x;
  const int b = f & 7;
  const int q = f >> 3;
  const int n0 = (q & 7) * 128;
  const int rt = 15 - (q >> 3);   // long K first
  const int i0 = rt * 128;
  const int nkt = (rt + 1) * 2;
  const unsigned short* Ag = P + (size_t)b * Tn * Tn + (size_t)i0 * Tn;
  const unsigned short* Bg = Vt + (size_t)b * Tn * Hn + (size_t)n0 * Tn;
  __shared__ unsigned short lds[2][4][128 * 32];
  const int tid = threadIdx.x;
  const int lane = tid & 63, wave = tid >> 6;
  const int wr = (wave >> 1) * 64, wc = (wave & 1) * 64;
  const int rl15 = lane & 15, l4 = lane >> 4;
  const int csw = (l4 ^ (lane & 3) ^ ((lane >> 2) & 3)) & 3;

  f32x4 acc[4][4];
#pragma unroll
  for (int m = 0; m < 4; ++m)
#pragma unroll
    for (int n = 0; n < 4; ++n) acc[m][n] = (f32x4)(0.f);

  bf16x8 a0[4], b0[4];
  auto M16 = [&]() {
    __builtin_amdgcn_s_setprio(1);
#pragma unroll
    for (int m = 0; m < 4; ++m)
#pragma unroll
      for (int n = 0; n < 4; ++n)
        acc[m][n] = __builtin_amdgcn_mfma_f32_16x16x32_bf16(a0[m], b0[n], acc[m][n], 0, 0, 0);
    __builtin_amdgcn_s_setprio(0);
  };

  stage128x32s(Ag +  0, Tn, &lds[0][0][0], wave, lane);
  stage128x32s(Bg +  0, Tn, &lds[0][2][0], wave, lane);
  stage128x32s(Ag + 32, Tn, &lds[0][1][0], wave, lane);
  stage128x32s(Bg + 32, Tn, &lds[0][3][0], wave, lane);
  stage128x32s(Ag + 64, Tn, &lds[1][0][0], wave, lane);
  stage128x32s(Bg + 64, Tn, &lds[1][2][0], wave, lane);
  QKV_VM8; QKV_BAR;

#pragma unroll 1
  for (int t = 0; t < nkt; ++t) {
    const int cb = t & 1, nb = cb ^ 1;
    rd4(&lds[cb][0][0], wr, rl15, csw, a0);
    rd4(&lds[cb][2][0], wc, rl15, csw, b0);
    {
      const int ts = (t + 1 < nkt) ? t + 1 : nkt - 1;
      stage128x32s(Ag + ts * 64 + 32, Tn, &lds[nb][1][0], wave, lane);
      stage128x32s(Bg + ts * 64 + 32, Tn, &lds[nb][3][0], wave, lane);
    }
    QKV_VM8; QKV_BAR; QKV_LGKM; M16(); QKV_BAR;
    rd4(&lds[cb][1][0], wr, rl15, csw, a0);
    rd4(&lds[cb][3][0], wc, rl15, csw, b0);
    {
      const int ts = (t + 2 < nkt) ? t + 2 : nkt - 1;
      stage128x32s(Ag + ts * 64, Tn, &lds[cb][0][0], wave, lane);
      stage128x32s(Bg + ts * 64, Tn, &lds[cb][2][0], wave, lane);
    }
    QKV_VM8; QKV_BAR; QKV_LGKM; M16(); QKV_BAR;
  }
  QKV_VM0;

#pragma unroll
  for (int m = 0; m < 4; ++m) {
    const int rb = i0 + wr + m * 16 + l4 * 4;   // % 4 == 0
    float4 lv = *(const float4*)&lbuf[(size_t)b * Tn + rb];
    const float inv0 = 1.f / lv.x, inv1 = 1.f / lv.y, inv2 = 1.f / lv.z, inv3 = 1.f / lv.w;
#pragma unroll
    for (int n = 0; n < 4; ++n) {
      const int col = n0 + wc + n * 16 + rl15;
      O[((size_t)b * Tn + rb + 0) * Hn + col] = acc[m][n][0] * inv0;
      O[((size_t)b * Tn + rb + 1) * Hn + col] = acc[m][n][1] * inv1;
      O[((size_t)b * Tn + rb + 2) * Hn + col] = acc[m][n][2] * inv2;
      O[((size_t)b * Tn + rb + 3) * Hn + col] = acc[m][n][3] * inv3;
    }
  }
}

extern "C" void kernel_launch(void* const* d_in, const int* in_sizes, int n_in,
                              void* d_out, int out_size, void* d_ws, size_t ws_size,
                              hipStream_t stream) {
  const float* x  = (const float*)d_in[0];
  const float* Wq = (const float*)d_in[1];
  const float* Wk = (const float*)d_in[2];
  const float* Wv = (const float*)d_in[3];
  float* out = (float*)d_out;

  // workspace layout (bytes); total 198 MiB
  char* ws = (char*)d_ws;
  const size_t MiB = 1024 * 1024;
  unsigned short* Wt3 = (unsigned short*)(ws + 0 * MiB);    // 3 x 2 MiB, stacked q,k,v
  unsigned short* xb  = (unsigned short*)(ws + 6 * MiB);    // 32 MiB; dead after projections
  unsigned short* Qb  = (unsigned short*)(ws + 38 * MiB);
  unsigned short* Kb  = (unsigned short*)(ws + 70 * MiB);
  unsigned short* Vt  = (unsigned short*)(ws + 102 * MiB);  // V, transposed per-batch [h][t]
  unsigned short* S   = (unsigned short*)(ws + 134 * MiB);  // 64 MiB, holds E = exp(scores)
  float*          lrow = (float*)(ws + 6 * MiB);            // 64 KiB in xb's dead region

  // 1. convert x to bf16
  {
    int n4 = (Mn * Dn) / 4;
    k_convert<<<dim3(n4 / 256), 256, 0, stream>>>(x, xb, n4);
  }
  // 2. convert+transpose all 3 weights (one dispatch)
  {
    dim3 g(Hn / 64, Dn / 64, 3);
    k_cvt_w_t<<<g, 256, 0, stream>>>(Wq, Wk, Wv, Wt3);
  }
  // 3. merged Q/K/V projections (V stored transposed), 2-phase/K-tile pipelined 256^2 tiles
  {
    gemm_qkv<<<dim3(768), 512, 0, stream>>>(xb, Wt3, Qb, Kb, Vt);
  }
  // 4. zero denominators (lrow aliases xb; qkv is done with xb by here in-stream)
  hipMemsetAsync(lrow, 0, (size_t)Bn * Tn * sizeof(float), stream);
  // 5. scores -> E = exp(s), causal-masked, with fused row sums (triangular grid)
  {
    gemm_scores<<<dim3(1088), 256, 0, stream>>>(Qb, Kb, S, lrow);
  }
  // 6. output with 1/l scaling
  {
    gemm_out<<<dim3(1024), 256, 0, stream>>>(S, Vt, lrow, out);
  }
}